// Round 1
// baseline (713.236 us; speedup 1.0000x reference)
//
#include <hip/hip_runtime.h>
#include <cstdint>
#include <cstddef>

#define MROWS 1024
#define NCOLS 4096

// ---------------- wave (64-lane) reduce helpers ----------------
__device__ inline float wave_max_f(float v) {
    #pragma unroll
    for (int off = 32; off >= 1; off >>= 1)
        v = fmaxf(v, __shfl_xor(v, off, 64));
    return v;
}
__device__ inline float wave_sum_f(float v) {
    #pragma unroll
    for (int off = 32; off >= 1; off >>= 1)
        v += __shfl_xor(v, off, 64);
    return v;
}

// ---------------- K1: per-block partial max over scores ----------------
__global__ __launch_bounds__(256) void k_partial_max(const float* __restrict__ s,
                                                     float* __restrict__ pmax) {
    int b = blockIdx.x, t = threadIdx.x;
    const float4* s4 = (const float4*)s;
    float m = -3.4e38f;
    int base = b * 4096 + t;  // float4 index; block covers 16384 floats
    #pragma unroll
    for (int i = 0; i < 16; ++i) {
        float4 v = s4[base + i * 256];
        m = fmaxf(m, fmaxf(fmaxf(v.x, v.y), fmaxf(v.z, v.w)));
    }
    m = wave_max_f(m);
    __shared__ float sm[4];
    if ((t & 63) == 0) sm[t >> 6] = m;
    __syncthreads();
    if (t == 0) pmax[b] = fmaxf(fmaxf(sm[0], sm[1]), fmaxf(sm[2], sm[3]));
}

// ---------------- K2: finalize global max ----------------
__global__ __launch_bounds__(256) void k_final_max(const float* __restrict__ pmax,
                                                   float* __restrict__ gmax) {
    int t = threadIdx.x;
    float m = pmax[t];
    m = wave_max_f(m);
    __shared__ float sm[4];
    if ((t & 63) == 0) sm[t >> 6] = m;
    __syncthreads();
    if (t == 0) gmax[0] = fmaxf(fmaxf(sm[0], sm[1]), fmaxf(sm[2], sm[3]));
}

// ---------------- K3: per-block partial sum of exp(s - gmax) ----------------
__global__ __launch_bounds__(256) void k_partial_sum(const float* __restrict__ s,
                                                     const float* __restrict__ gmaxp,
                                                     float* __restrict__ psum) {
    int b = blockIdx.x, t = threadIdx.x;
    float gmax = gmaxp[0];
    const float4* s4 = (const float4*)s;
    float acc = 0.0f;
    int base = b * 4096 + t;
    #pragma unroll
    for (int i = 0; i < 16; ++i) {
        float4 v = s4[base + i * 256];
        acc += expf(v.x - gmax) + expf(v.y - gmax) + expf(v.z - gmax) + expf(v.w - gmax);
    }
    acc = wave_sum_f(acc);
    __shared__ float sm[4];
    if ((t & 63) == 0) sm[t >> 6] = acc;
    __syncthreads();
    if (t == 0) psum[b] = sm[0] + sm[1] + sm[2] + sm[3];
}

// ---------------- K4: finalize sum + build consumed-column bitmap ----------------
__global__ __launch_bounds__(256) void k_final_sum_bitmap(const float* __restrict__ psum,
                                                          float* __restrict__ gsum,
                                                          unsigned* __restrict__ bitmap,
                                                          const int* __restrict__ cont,
                                                          const int* __restrict__ prev) {
    int t = threadIdx.x;
    float v = psum[t];
    v = wave_sum_f(v);
    __shared__ float sm[4];
    if ((t & 63) == 0) sm[t >> 6] = v;
    if (t < 128) bitmap[t] = 0u;   // zero before atomicOr; ordered by barrier below
    __syncthreads();
    if (t == 0) gsum[0] = sm[0] + sm[1] + sm[2] + sm[3];
    for (int i = t; i < MROWS; i += 256) {
        if (cont[i]) {
            int c = prev[i];
            atomicOr(&bitmap[c >> 5], 1u << (c & 31));
        }
    }
}

// ---------------- K5: write policy + per-row masked top-2 keys ----------------
// key = (float_bits(p) << 32) | (NCOLS-1-col): u64 max == value-desc, col-asc.
__global__ __launch_bounds__(256) void k_policy_rowtop2(const float* __restrict__ s,
                                                        const float* __restrict__ gmaxp,
                                                        const float* __restrict__ gsump,
                                                        const unsigned* __restrict__ bitmap,
                                                        const int* __restrict__ cont,
                                                        float* __restrict__ policy,
                                                        unsigned long long* __restrict__ key1,
                                                        unsigned long long* __restrict__ key2) {
    int r = blockIdx.x, t = threadIdx.x;
    float gmax = gmaxp[0];
    float gsum = gsump[0];
    int cg = cont[r];
    const float* srow = s + (size_t)r * NCOLS;
    float* prow = policy + (size_t)r * NCOLS;
    unsigned long long k1 = 0ull, k2 = 0ull;
    #pragma unroll
    for (int i = 0; i < 16; ++i) {
        int c = t + i * 256;
        float p = expf(srow[c] - gmax) / gsum;
        prow[c] = p;
        if (!cg && !((bitmap[c >> 5] >> (c & 31)) & 1u)) {
            unsigned long long kk =
                ((unsigned long long)__float_as_uint(p) << 32) | (unsigned)(NCOLS - 1 - c);
            if (kk > k1) { k2 = k1; k1 = kk; }
            else if (kk > k2) { k2 = kk; }
        }
    }
    // wave top-2 merge
    #pragma unroll
    for (int off = 32; off >= 1; off >>= 1) {
        unsigned long long o1 = __shfl_xor(k1, off, 64);
        unsigned long long o2 = __shfl_xor(k2, off, 64);
        if (o1 > k1) { k2 = (k1 > o2 ? k1 : o2); k1 = o1; }
        else { k2 = (k2 > o1 ? k2 : o1); }
    }
    __shared__ unsigned long long s1[4], s2[4];
    if ((t & 63) == 0) { s1[t >> 6] = k1; s2[t >> 6] = k2; }
    __syncthreads();
    if (t == 0) {
        unsigned long long a1 = s1[0], a2 = s2[0];
        #pragma unroll
        for (int w = 1; w < 4; ++w) {
            unsigned long long b1 = s1[w], b2 = s2[w];
            if (b1 > a1) { a2 = (a1 > b2 ? a1 : b2); a1 = b1; }
            else { a2 = (a2 > b1 ? a2 : b1); }
        }
        key1[r] = a1;
        key2[r] = a2;
    }
}

// ---------------- K6: sequential greedy assignment (single wave) ----------------
__global__ __launch_bounds__(64) void k_assign(const int* __restrict__ cont,
                                               const int* __restrict__ prev,
                                               float* __restrict__ actions,
                                               const float* __restrict__ policy,
                                               const unsigned* __restrict__ g_bitmap,
                                               const unsigned long long* __restrict__ g_key1,
                                               const unsigned long long* __restrict__ g_key2) {
    __shared__ unsigned long long k1s[MROWS];
    __shared__ unsigned long long k2s[MROWS];
    __shared__ unsigned bm[128];
    int lane = threadIdx.x;

    int K = 0;
    #pragma unroll
    for (int j = 0; j < 16; ++j) {
        int i = j * 64 + lane;
        k1s[i] = g_key1[i];
        k2s[i] = g_key2[i];
        int cg = cont[i];
        actions[i] = cg ? (float)prev[i] : -1.0f;
        K += (cg == 0);
    }
    bm[lane] = g_bitmap[lane];
    bm[lane + 64] = g_bitmap[lane + 64];
    #pragma unroll
    for (int off = 32; off >= 1; off >>= 1) K += __shfl_xor(K, off, 64);
    __syncthreads();

    int assigned = 0;
    for (int guard = 0; guard < (1 << 20) && assigned < K; ++guard) {
        // global argmax over row keys: value-desc, then row-asc (matches flat-index tiebreak)
        unsigned long long bk = 0ull;
        int br = 0;
        #pragma unroll
        for (int j = 0; j < 16; ++j) {
            int row = j * 64 + lane;
            unsigned long long kk = k1s[row];
            if ((kk >> 32) > (bk >> 32)) { bk = kk; br = row; }  // ascending row: tie keeps earlier
        }
        #pragma unroll
        for (int off = 32; off >= 1; off >>= 1) {
            unsigned long long ok = __shfl_xor(bk, off, 64);
            int orr = __shfl_xor(br, off, 64);
            unsigned vo = (unsigned)(ok >> 32), vb = (unsigned)(bk >> 32);
            if (vo > vb || (vo == vb && orr < br)) { bk = ok; br = orr; }
        }
        if (bk == 0ull) break;

        int col = (NCOLS - 1) - (int)(unsigned)(bk & 0xFFFFFFFFull);
        int row = br;
        bool consumed = (bm[col >> 5] >> (col & 31)) & 1u;
        if (!consumed) {
            // valid greedy pick
            if (lane == 0) {
                actions[row] = (float)col;
                bm[col >> 5] |= (1u << (col & 31));
                k1s[row] = 0ull;
                k2s[row] = 0ull;
            }
            ++assigned;
        } else {
            unsigned long long k2 = k2s[row];
            int col2 = (NCOLS - 1) - (int)(unsigned)(k2 & 0xFFFFFFFFull);
            bool ok2 = (k2 != 0ull) && !((bm[col2 >> 5] >> (col2 & 31)) & 1u);
            if (ok2) {
                // promote second-best (still the true current row max)
                if (lane == 0) { k1s[row] = k2; k2s[row] = 0ull; }
            } else {
                // cooperative rescan of this row over unconsumed columns
                const float* prow = policy + (size_t)row * NCOLS;
                unsigned long long t1 = 0ull, t2 = 0ull;
                #pragma unroll 4
                for (int i2 = 0; i2 < 64; ++i2) {
                    int c = i2 * 64 + lane;
                    float p = prow[c];
                    if (!((bm[c >> 5] >> (c & 31)) & 1u)) {
                        unsigned long long kk =
                            ((unsigned long long)__float_as_uint(p) << 32) |
                            (unsigned)((NCOLS - 1) - c);
                        if (kk > t1) { t2 = t1; t1 = kk; }
                        else if (kk > t2) { t2 = kk; }
                    }
                }
                #pragma unroll
                for (int off = 32; off >= 1; off >>= 1) {
                    unsigned long long o1 = __shfl_xor(t1, off, 64);
                    unsigned long long o2 = __shfl_xor(t2, off, 64);
                    if (o1 > t1) { t2 = (t1 > o2 ? t1 : o2); t1 = o1; }
                    else { t2 = (t2 > o1 ? t2 : o1); }
                }
                if (lane == 0) { k1s[row] = t1; k2s[row] = t2; }
            }
        }
        __syncthreads();
    }
}

extern "C" void kernel_launch(void* const* d_in, const int* in_sizes, int n_in,
                              void* d_out, int out_size, void* d_ws, size_t ws_size,
                              hipStream_t stream) {
    (void)in_sizes; (void)n_in; (void)out_size; (void)ws_size;
    const float* scores = (const float*)d_in[0];
    const int* cont = (const int*)d_in[1];
    const int* prev = (const int*)d_in[2];
    float* out = (float*)d_out;
    float* actions = out;           // MROWS entries (actions as float)
    float* policy = out + MROWS;    // MROWS*NCOLS entries

    char* ws = (char*)d_ws;
    float* pmax = (float*)(ws + 0);          // 256 floats
    float* psum = (float*)(ws + 1024);       // 256 floats
    float* gmax = (float*)(ws + 2048);       // 1 float
    float* gsum = (float*)(ws + 2052);       // 1 float
    unsigned* bitmap = (unsigned*)(ws + 2304);               // 128 u32
    unsigned long long* key1 = (unsigned long long*)(ws + 4096);   // 1024 u64
    unsigned long long* key2 = (unsigned long long*)(ws + 12288);  // 1024 u64

    k_partial_max<<<256, 256, 0, stream>>>(scores, pmax);
    k_final_max<<<1, 256, 0, stream>>>(pmax, gmax);
    k_partial_sum<<<256, 256, 0, stream>>>(scores, gmax, psum);
    k_final_sum_bitmap<<<1, 256, 0, stream>>>(psum, gsum, bitmap, cont, prev);
    k_policy_rowtop2<<<MROWS, 256, 0, stream>>>(scores, gmax, gsum, bitmap, cont,
                                                policy, key1, key2);
    k_assign<<<1, 64, 0, stream>>>(cont, prev, actions, policy, bitmap, key1, key2);
}

// Round 2
// 338.608 us; speedup vs baseline: 2.1064x; 2.1064x over previous
//
#include <hip/hip_runtime.h>
#include <cstdint>
#include <cstddef>

#define MROWS 1024
#define NCOLS 4096
#define TOPK 16
#define NKEYS (MROWS * TOPK)   // 16384
#define HALF (NKEYS / 2)       // 8192

typedef unsigned long long u64;

// key = (p_bits << 22) | ((1023-row) << 12) | (4095-col)
// u64 descending == p desc, then row asc, then col asc (flat-index tie-break).
__device__ inline int key_col(u64 k) { return (NCOLS - 1) - (int)(k & 0xFFFull); }
__device__ inline int key_row(u64 k) { return (MROWS - 1) - (int)((k >> 12) & 0x3FFull); }

// ---------------- wave (64-lane) reduce helpers ----------------
__device__ inline float wave_max_f(float v) {
    #pragma unroll
    for (int off = 32; off >= 1; off >>= 1)
        v = fmaxf(v, __shfl_xor(v, off, 64));
    return v;
}
__device__ inline float wave_sum_f(float v) {
    #pragma unroll
    for (int off = 32; off >= 1; off >>= 1)
        v += __shfl_xor(v, off, 64);
    return v;
}
__device__ inline u64 wave_max_u64(u64 v) {
    #pragma unroll
    for (int off = 32; off >= 1; off >>= 1) {
        u64 o = __shfl_xor(v, off, 64);
        v = o > v ? o : v;
    }
    return v;
}

// ---------------- K1: per-block partial max over scores ----------------
__global__ __launch_bounds__(256) void k_partial_max(const float* __restrict__ s,
                                                     float* __restrict__ pmax) {
    int b = blockIdx.x, t = threadIdx.x;
    const float4* s4 = (const float4*)s;
    float m = -3.4e38f;
    int base = b * 4096 + t;
    #pragma unroll
    for (int i = 0; i < 16; ++i) {
        float4 v = s4[base + i * 256];
        m = fmaxf(m, fmaxf(fmaxf(v.x, v.y), fmaxf(v.z, v.w)));
    }
    m = wave_max_f(m);
    __shared__ float sm[4];
    if ((t & 63) == 0) sm[t >> 6] = m;
    __syncthreads();
    if (t == 0) pmax[b] = fmaxf(fmaxf(sm[0], sm[1]), fmaxf(sm[2], sm[3]));
}

// ---------------- K2: finalize global max ----------------
__global__ __launch_bounds__(256) void k_final_max(const float* __restrict__ pmax,
                                                   float* __restrict__ gmax) {
    int t = threadIdx.x;
    float m = pmax[t];
    m = wave_max_f(m);
    __shared__ float sm[4];
    if ((t & 63) == 0) sm[t >> 6] = m;
    __syncthreads();
    if (t == 0) gmax[0] = fmaxf(fmaxf(sm[0], sm[1]), fmaxf(sm[2], sm[3]));
}

// ---------------- K3: per-block partial sum of exp(s - gmax) ----------------
__global__ __launch_bounds__(256) void k_partial_sum(const float* __restrict__ s,
                                                     const float* __restrict__ gmaxp,
                                                     float* __restrict__ psum) {
    int b = blockIdx.x, t = threadIdx.x;
    float gmax = gmaxp[0];
    const float4* s4 = (const float4*)s;
    float acc = 0.0f;
    int base = b * 4096 + t;
    #pragma unroll
    for (int i = 0; i < 16; ++i) {
        float4 v = s4[base + i * 256];
        acc += expf(v.x - gmax) + expf(v.y - gmax) + expf(v.z - gmax) + expf(v.w - gmax);
    }
    acc = wave_sum_f(acc);
    __shared__ float sm[4];
    if ((t & 63) == 0) sm[t >> 6] = acc;
    __syncthreads();
    if (t == 0) psum[b] = sm[0] + sm[1] + sm[2] + sm[3];
}

// ---------------- K4: finalize sum + consumed-column bitmap ----------------
__global__ __launch_bounds__(256) void k_final_sum_bitmap(const float* __restrict__ psum,
                                                          float* __restrict__ gsum,
                                                          unsigned* __restrict__ bitmap,
                                                          const int* __restrict__ cont,
                                                          const int* __restrict__ prev) {
    int t = threadIdx.x;
    float v = psum[t];
    v = wave_sum_f(v);
    __shared__ float sm[4];
    if ((t & 63) == 0) sm[t >> 6] = v;
    if (t < 128) bitmap[t] = 0u;
    __syncthreads();
    if (t == 0) gsum[0] = sm[0] + sm[1] + sm[2] + sm[3];
    for (int i = t; i < MROWS; i += 256) {
        if (cont[i]) {
            int c = prev[i];
            atomicOr(&bitmap[c >> 5], 1u << (c & 31));
        }
    }
}

// ---------------- K5: write policy + per-row masked top-16 keys ----------------
__global__ __launch_bounds__(256) void k_policy_top16(const float* __restrict__ s,
                                                      const float* __restrict__ gmaxp,
                                                      const float* __restrict__ gsump,
                                                      const unsigned* __restrict__ bitmap,
                                                      const int* __restrict__ cont,
                                                      float* __restrict__ policy,
                                                      u64* __restrict__ outkeys) {
    __shared__ u64 keys[NCOLS];   // 32 KiB
    __shared__ u64 red[4];
    int r = blockIdx.x, t = threadIdx.x;
    float gmax = gmaxp[0];
    float gsum = gsump[0];
    int cg = cont[r];
    const float* srow = s + (size_t)r * NCOLS;
    float* prow = policy + (size_t)r * NCOLS;
    u64 rowpart = (u64)(MROWS - 1 - r) << 12;
    #pragma unroll
    for (int i = 0; i < 16; ++i) {
        int c = t + i * 256;
        float p = expf(srow[c] - gmax) / gsum;
        prow[c] = p;
        u64 kk = 0ull;
        if (!cg && !((bitmap[c >> 5] >> (c & 31)) & 1u))
            kk = ((u64)__float_as_uint(p) << 22) | rowpart | (u64)(NCOLS - 1 - c);
        keys[c] = kk;
    }
    __syncthreads();
    if (cg) {
        if (t < TOPK) outkeys[r * TOPK + t] = 0ull;
        return;
    }
    for (int pass = 0; pass < TOPK; ++pass) {
        u64 best = 0ull;
        #pragma unroll
        for (int i = 0; i < 16; ++i) {
            u64 kk = keys[t + i * 256];
            best = kk > best ? kk : best;
        }
        best = wave_max_u64(best);
        if ((t & 63) == 0) red[t >> 6] = best;
        __syncthreads();
        if (t == 0) {
            u64 b0 = red[0] > red[1] ? red[0] : red[1];
            u64 b1 = red[2] > red[3] ? red[2] : red[3];
            u64 b = b0 > b1 ? b0 : b1;
            outkeys[r * TOPK + pass] = b;
            keys[key_col(b)] = 0ull;   // remove winner (b != 0 always: >=3072 valid cols)
        }
        __syncthreads();
    }
}

// ---------------- K6a: bitonic sort each half (k=2..8192) in LDS ----------------
__global__ __launch_bounds__(1024) void k_sort_half(u64* __restrict__ keys) {
    __shared__ u64 sk[HALF];   // 64 KiB
    int t = threadIdx.x;
    int off = blockIdx.x * HALF;
    for (int i = t; i < HALF; i += 1024) sk[i] = keys[off + i];
    __syncthreads();
    for (int k = 2; k <= HALF; k <<= 1) {
        for (int j = k >> 1; j >= 1; j >>= 1) {
            for (int idx = t; idx < HALF / 2; idx += 1024) {
                int i = ((idx & ~(j - 1)) << 1) | (idx & (j - 1));
                int p = i | j;
                bool desc = (((off + i) & k) == 0);   // global-index direction
                u64 a = sk[i], b = sk[p];
                bool sw = desc ? (a < b) : (a > b);
                if (sw) { sk[i] = b; sk[p] = a; }
            }
            __syncthreads();
        }
    }
    for (int i = t; i < HALF; i += 1024) keys[off + i] = sk[i];
}

// ---------------- K6b: global cross-half pass (k=16384, j=8192, all desc) -------
__global__ __launch_bounds__(256) void k_sort_gpass(u64* __restrict__ keys) {
    int i = blockIdx.x * 256 + threadIdx.x;   // 0..8191
    u64 a = keys[i], b = keys[i + HALF];
    if (a < b) { keys[i] = b; keys[i + HALF] = a; }
}

// ---------------- K6c: finish merge (j=4096..1, all desc) in LDS ----------------
__global__ __launch_bounds__(1024) void k_sort_merge(u64* __restrict__ keys) {
    __shared__ u64 sk[HALF];   // 64 KiB
    int t = threadIdx.x;
    int off = blockIdx.x * HALF;
    for (int i = t; i < HALF; i += 1024) sk[i] = keys[off + i];
    __syncthreads();
    for (int j = HALF / 2; j >= 1; j >>= 1) {
        for (int idx = t; idx < HALF / 2; idx += 1024) {
            int i = ((idx & ~(j - 1)) << 1) | (idx & (j - 1));
            int p = i | j;
            u64 a = sk[i], b = sk[p];
            if (a < b) { sk[i] = b; sk[p] = a; }   // descending everywhere
        }
        __syncthreads();
    }
    for (int i = t; i < HALF; i += 1024) keys[off + i] = sk[i];
}

// ---------------- K7: single-wave serial scan of the sorted list ----------------
__global__ __launch_bounds__(64) void k_scan(const int* __restrict__ cont,
                                             const int* __restrict__ prev,
                                             float* __restrict__ actions,
                                             const u64* __restrict__ sorted,
                                             const unsigned* __restrict__ bitmap,
                                             const float* __restrict__ policy) {
    __shared__ unsigned rowdone[MROWS / 32];   // 32
    __shared__ unsigned coldone[NCOLS / 32];   // 128
    int lane = threadIdx.x;
    if (lane < 32) rowdone[lane] = 0u;
    coldone[lane] = bitmap[lane];
    coldone[lane + 64] = bitmap[lane + 64];
    __syncthreads();
    int K = 0;
    #pragma unroll
    for (int j = 0; j < 16; ++j) {
        int i = j * 64 + lane;
        int cg = cont[i];
        actions[i] = cg ? (float)prev[i] : -1.0f;
        if (cg) atomicOr(&rowdone[i >> 5], 1u << (i & 31));
        K += (cg == 0);
    }
    #pragma unroll
    for (int off = 32; off >= 1; off >>= 1) K += __shfl_xor(K, off, 64);
    __syncthreads();

    int assigned = 0;
    for (int base = 0; base < NKEYS && assigned < K; base += 64) {
        u64 key = sorted[base + lane];
        bool valid = key != 0ull;
        if (__ballot(valid) == 0ull) break;   // rest of list is zero-padding
        int row = key_row(key);
        int col = key_col(key);
        bool rfree = valid && !((rowdone[row >> 5] >> (row & 31)) & 1u);
        bool cfree = valid && !((coldone[col >> 5] >> (col & 31)) & 1u);
        u64 cand = __ballot(rfree && cfree);
        while (cand != 0ull && assigned < K) {
            int i = __ffsll((long long)cand) - 1;
            cand &= cand - 1ull;
            bool doit = false;
            if (lane == i) {
                // authoritative re-check (snapshot may be stale within batch)
                if (!((rowdone[row >> 5] >> (row & 31)) & 1u) &&
                    !((coldone[col >> 5] >> (col & 31)) & 1u)) {
                    rowdone[row >> 5] |= 1u << (row & 31);
                    coldone[col >> 5] |= 1u << (col & 31);
                    actions[row] = (float)col;
                    doit = true;
                }
            }
            assigned += (__ballot(doit) != 0ull) ? 1 : 0;
        }
    }

    // Exact-greedy fallback for rows that exhausted their top-16 (P ~ 2e-10).
    for (int guard = 0; assigned < K && guard < 2048; ++guard) {
        u64 best = 0ull;
        for (int r = 0; r < MROWS; ++r) {
            if ((rowdone[r >> 5] >> (r & 31)) & 1u) continue;
            const float* prow = policy + (size_t)r * NCOLS;
            u64 rowpart = (u64)(MROWS - 1 - r) << 12;
            for (int c = lane; c < NCOLS; c += 64) {
                if ((coldone[c >> 5] >> (c & 31)) & 1u) continue;
                u64 kk = ((u64)__float_as_uint(prow[c]) << 22) | rowpart |
                         (u64)(NCOLS - 1 - c);
                best = kk > best ? kk : best;
            }
        }
        best = wave_max_u64(best);
        if (best == 0ull) break;
        if (lane == 0) {
            int row = key_row(best), col = key_col(best);
            rowdone[row >> 5] |= 1u << (row & 31);
            coldone[col >> 5] |= 1u << (col & 31);
            actions[row] = (float)col;
        }
        ++assigned;
    }
}

extern "C" void kernel_launch(void* const* d_in, const int* in_sizes, int n_in,
                              void* d_out, int out_size, void* d_ws, size_t ws_size,
                              hipStream_t stream) {
    (void)in_sizes; (void)n_in; (void)out_size; (void)ws_size;
    const float* scores = (const float*)d_in[0];
    const int* cont = (const int*)d_in[1];
    const int* prev = (const int*)d_in[2];
    float* out = (float*)d_out;
    float* actions = out;
    float* policy = out + MROWS;

    char* ws = (char*)d_ws;
    float* pmax = (float*)(ws + 0);            // 256 f
    float* psum = (float*)(ws + 1024);         // 256 f
    float* gmax = (float*)(ws + 2048);         // 1 f
    float* gsum = (float*)(ws + 2052);         // 1 f
    unsigned* bitmap = (unsigned*)(ws + 2304); // 128 u32
    u64* keys16 = (u64*)(ws + 4096);           // 16384 u64 (sorted in place)

    k_partial_max<<<256, 256, 0, stream>>>(scores, pmax);
    k_final_max<<<1, 256, 0, stream>>>(pmax, gmax);
    k_partial_sum<<<256, 256, 0, stream>>>(scores, gmax, psum);
    k_final_sum_bitmap<<<1, 256, 0, stream>>>(psum, gsum, bitmap, cont, prev);
    k_policy_top16<<<MROWS, 256, 0, stream>>>(scores, gmax, gsum, bitmap, cont,
                                              policy, keys16);
    k_sort_half<<<2, 1024, 0, stream>>>(keys16);
    k_sort_gpass<<<HALF / 256, 256, 0, stream>>>(keys16);
    k_sort_merge<<<2, 1024, 0, stream>>>(keys16);
    k_scan<<<1, 64, 0, stream>>>(cont, prev, actions, keys16, bitmap, policy);
}

// Round 3
// 243.093 us; speedup vs baseline: 2.9340x; 1.3929x over previous
//
#include <hip/hip_runtime.h>
#include <cstdint>
#include <cstddef>

#define MROWS 1024
#define NCOLS 4096
#define TOPK 16
#define NKEYS (MROWS * TOPK)   // 16384
#define CHUNK 4096             // local-sort span

typedef unsigned long long u64;

// key = (p_bits << 22) | ((1023-row) << 12) | (4095-col)
// u64 descending == p desc, then row asc, then col asc (flat-index tie-break).
__device__ inline int key_col(u64 k) { return (NCOLS - 1) - (int)(k & 0xFFFull); }
__device__ inline int key_row(u64 k) { return (MROWS - 1) - (int)((k >> 12) & 0x3FFull); }

// ---------------- wave (64-lane) reduce helpers ----------------
__device__ inline float wave_max_f(float v) {
    #pragma unroll
    for (int off = 32; off >= 1; off >>= 1)
        v = fmaxf(v, __shfl_xor(v, off, 64));
    return v;
}
__device__ inline float wave_sum_f(float v) {
    #pragma unroll
    for (int off = 32; off >= 1; off >>= 1)
        v += __shfl_xor(v, off, 64);
    return v;
}
__device__ inline u64 wave_max_u64(u64 v) {
    #pragma unroll
    for (int off = 32; off >= 1; off >>= 1) {
        u64 o = __shfl_xor(v, off, 64);
        v = o > v ? o : v;
    }
    return v;
}

// ---------------- K1: per-block partial max over scores ----------------
__global__ __launch_bounds__(256) void k_partial_max(const float* __restrict__ s,
                                                     float* __restrict__ pmax) {
    int b = blockIdx.x, t = threadIdx.x;
    const float4* s4 = (const float4*)s;
    float m = -3.4e38f;
    int base = b * 4096 + t;
    #pragma unroll
    for (int i = 0; i < 16; ++i) {
        float4 v = s4[base + i * 256];
        m = fmaxf(m, fmaxf(fmaxf(v.x, v.y), fmaxf(v.z, v.w)));
    }
    m = wave_max_f(m);
    __shared__ float sm[4];
    if ((t & 63) == 0) sm[t >> 6] = m;
    __syncthreads();
    if (t == 0) pmax[b] = fmaxf(fmaxf(sm[0], sm[1]), fmaxf(sm[2], sm[3]));
}

// ---------------- K2: inline gmax + partial sum of exp; block0 builds bitmap ----
__global__ __launch_bounds__(256) void k_partial_sum2(const float* __restrict__ s,
                                                      const float* __restrict__ pmax,
                                                      float* __restrict__ psum,
                                                      unsigned* __restrict__ bitmap,
                                                      const int* __restrict__ cont,
                                                      const int* __restrict__ prev) {
    int b = blockIdx.x, t = threadIdx.x;
    __shared__ float fred[4];
    if (b == 0 && t < 128) bitmap[t] = 0u;
    // inline global-max reduction over the 256 partials
    float m = pmax[t];
    m = wave_max_f(m);
    if ((t & 63) == 0) fred[t >> 6] = m;
    __syncthreads();
    float gmax = fmaxf(fmaxf(fred[0], fred[1]), fmaxf(fred[2], fred[3]));

    const float4* s4 = (const float4*)s;
    float acc = 0.0f;
    int base = b * 4096 + t;
    #pragma unroll
    for (int i = 0; i < 16; ++i) {
        float4 v = s4[base + i * 256];
        acc += expf(v.x - gmax) + expf(v.y - gmax) + expf(v.z - gmax) + expf(v.w - gmax);
    }
    acc = wave_sum_f(acc);
    __syncthreads();
    if ((t & 63) == 0) fred[t >> 6] = acc;
    __syncthreads();
    if (t == 0) psum[b] = fred[0] + fred[1] + fred[2] + fred[3];
    if (b == 0) {
        // barrier above ordered the zeroing before these atomics
        for (int i = t; i < MROWS; i += 256) {
            if (cont[i]) {
                int c = prev[i];
                atomicOr(&bitmap[c >> 5], 1u << (c & 31));
            }
        }
    }
}

// ---------------- K3: policy write + per-row masked top-16 keys ----------------
__global__ __launch_bounds__(256) void k_policy_top16(const float* __restrict__ s,
                                                      const float* __restrict__ pmax,
                                                      const float* __restrict__ psum,
                                                      const unsigned* __restrict__ bitmap,
                                                      const int* __restrict__ cont,
                                                      float* __restrict__ policy,
                                                      u64* __restrict__ outkeys) {
    __shared__ u64 keys[NCOLS];   // 32 KiB
    __shared__ u64 red[4];
    __shared__ float fred[4];
    int r = blockIdx.x, t = threadIdx.x;
    // inline gmax/gsum reductions (256 partials each)
    float m = pmax[t];
    m = wave_max_f(m);
    if ((t & 63) == 0) fred[t >> 6] = m;
    __syncthreads();
    float gmax = fmaxf(fmaxf(fred[0], fred[1]), fmaxf(fred[2], fred[3]));
    float sv = psum[t];
    sv = wave_sum_f(sv);
    __syncthreads();
    if ((t & 63) == 0) fred[t >> 6] = sv;
    __syncthreads();
    float gsum = fred[0] + fred[1] + fred[2] + fred[3];

    int cg = cont[r];
    const float* srow = s + (size_t)r * NCOLS;
    float* prow = policy + (size_t)r * NCOLS;
    u64 rowpart = (u64)(MROWS - 1 - r) << 12;
    #pragma unroll
    for (int i = 0; i < 16; ++i) {
        int c = t + i * 256;
        float p = expf(srow[c] - gmax) / gsum;
        prow[c] = p;
        u64 kk = 0ull;
        if (!cg && !((bitmap[c >> 5] >> (c & 31)) & 1u))
            kk = ((u64)__float_as_uint(p) << 22) | rowpart | (u64)(NCOLS - 1 - c);
        keys[c] = kk;
    }
    __syncthreads();
    if (cg) {
        if (t < TOPK) outkeys[r * TOPK + t] = 0ull;
        return;
    }
    for (int pass = 0; pass < TOPK; ++pass) {
        u64 best = 0ull;
        #pragma unroll
        for (int i = 0; i < 16; ++i) {
            u64 kk = keys[t + i * 256];
            best = kk > best ? kk : best;
        }
        best = wave_max_u64(best);
        if ((t & 63) == 0) red[t >> 6] = best;
        __syncthreads();
        if (t == 0) {
            u64 b0 = red[0] > red[1] ? red[0] : red[1];
            u64 b1 = red[2] > red[3] ? red[2] : red[3];
            u64 b = b0 > b1 ? b0 : b1;
            outkeys[r * TOPK + pass] = b;
            keys[key_col(b)] = 0ull;
        }
        __syncthreads();
    }
}

// ---------------- S1: local bitonic sort, 4 blocks x 4096 keys ----------------
__global__ __launch_bounds__(1024) void s1_localsort(u64* __restrict__ keys) {
    __shared__ u64 sk[CHUNK];   // 32 KiB
    int t = threadIdx.x;
    int off = blockIdx.x * CHUNK;
    for (int i = t; i < CHUNK; i += 1024) sk[i] = keys[off + i];
    __syncthreads();
    for (int k = 2; k <= CHUNK; k <<= 1) {
        for (int j = k >> 1; j >= 1; j >>= 1) {
            for (int idx = t; idx < CHUNK / 2; idx += 1024) {
                int i = ((idx & ~(j - 1)) << 1) | (idx & (j - 1));
                int p = i | j;
                bool desc = (((off + i) & k) == 0);
                u64 a = sk[i], b = sk[p];
                bool sw = desc ? (a < b) : (a > b);
                if (sw) { sk[i] = b; sk[p] = a; }
            }
            __syncthreads();
        }
    }
    for (int i = t; i < CHUNK; i += 1024) keys[off + i] = sk[i];
}

// ---------------- S2: global CE pass k=8192, j=4096 (register-only) -------------
__global__ __launch_bounds__(1024) void s2_gpass(u64* __restrict__ keys) {
    int idx = blockIdx.x * 1024 + threadIdx.x;           // 0..8191
    int i = ((idx >> 12) << 13) | (idx & 4095);          // 0..4095 or 8192..12287
    bool desc = ((i & 8192) == 0);
    u64 a = keys[i], b = keys[i + 4096];
    bool sw = desc ? (a < b) : (a > b);
    if (sw) { keys[i] = b; keys[i + 4096] = a; }
}

// ---------------- S3: local finish k=8192 (j<=2048), 4 blocks ------------------
__global__ __launch_bounds__(1024) void s3_localfinish(u64* __restrict__ keys) {
    __shared__ u64 sk[CHUNK];
    int t = threadIdx.x;
    int off = blockIdx.x * CHUNK;
    bool desc = ((off & 8192) == 0);   // uniform per block
    for (int i = t; i < CHUNK; i += 1024) sk[i] = keys[off + i];
    __syncthreads();
    for (int j = CHUNK / 2; j >= 1; j >>= 1) {
        for (int idx = t; idx < CHUNK / 2; idx += 1024) {
            int i = ((idx & ~(j - 1)) << 1) | (idx & (j - 1));
            int p = i | j;
            u64 a = sk[i], b = sk[p];
            bool sw = desc ? (a < b) : (a > b);
            if (sw) { sk[i] = b; sk[p] = a; }
        }
        __syncthreads();
    }
    for (int i = t; i < CHUNK; i += 1024) keys[off + i] = sk[i];
}

// ---------------- S45: k=16384, j=8192 then j=4096, fused in registers ---------
__global__ __launch_bounds__(1024) void s45_gpass(u64* __restrict__ keys) {
    int i = blockIdx.x * 1024 + threadIdx.x;   // 0..4095
    u64 a = keys[i], b = keys[i + 4096], c = keys[i + 8192], d = keys[i + 12288];
    u64 tmp;
    if (a < c) { tmp = a; a = c; c = tmp; }    // j=8192, desc
    if (b < d) { tmp = b; b = d; d = tmp; }
    if (a < b) { tmp = a; a = b; b = tmp; }    // j=4096, desc
    if (c < d) { tmp = c; c = d; d = tmp; }
    keys[i] = a; keys[i + 4096] = b; keys[i + 8192] = c; keys[i + 12288] = d;
}

// ---------------- S6: local finish (j<=2048, all desc), 4 blocks ---------------
__global__ __launch_bounds__(1024) void s6_localfinish(u64* __restrict__ keys) {
    __shared__ u64 sk[CHUNK];
    int t = threadIdx.x;
    int off = blockIdx.x * CHUNK;
    for (int i = t; i < CHUNK; i += 1024) sk[i] = keys[off + i];
    __syncthreads();
    for (int j = CHUNK / 2; j >= 1; j >>= 1) {
        for (int idx = t; idx < CHUNK / 2; idx += 1024) {
            int i = ((idx & ~(j - 1)) << 1) | (idx & (j - 1));
            int p = i | j;
            u64 a = sk[i], b = sk[p];
            if (a < b) { sk[i] = b; sk[p] = a; }
        }
        __syncthreads();
    }
    for (int i = t; i < CHUNK; i += 1024) keys[off + i] = sk[i];
}

// ---------------- K7: single-wave scan, ballot-resolved commits ----------------
__global__ __launch_bounds__(64) void k_scan(const int* __restrict__ cont,
                                             const int* __restrict__ prev,
                                             float* __restrict__ actions,
                                             const u64* __restrict__ sorted,
                                             const unsigned* __restrict__ bitmap,
                                             const float* __restrict__ policy) {
    __shared__ unsigned rowdone[MROWS / 32];   // 32
    __shared__ unsigned coldone[NCOLS / 32];   // 128
    int lane = threadIdx.x;
    if (lane < 32) rowdone[lane] = 0u;
    coldone[lane] = bitmap[lane];
    coldone[lane + 64] = bitmap[lane + 64];
    __syncthreads();
    int K = 0;
    #pragma unroll
    for (int j = 0; j < 16; ++j) {
        int i = j * 64 + lane;
        int cg = cont[i];
        actions[i] = cg ? (float)prev[i] : -1.0f;
        if (cg) atomicOr(&rowdone[i >> 5], 1u << (i & 31));
        K += (cg == 0);
    }
    #pragma unroll
    for (int off = 32; off >= 1; off >>= 1) K += __shfl_xor(K, off, 64);
    __syncthreads();

    int assigned = 0;
    u64 key = sorted[lane];
    for (int base = 0; base < NKEYS && assigned < K; base += 64) {
        u64 nkey = (base + 64 < NKEYS) ? sorted[base + 64 + lane] : 0ull;  // prefetch
        bool valid = key != 0ull;
        if (__ballot(valid) == 0ull) break;
        int row = key_row(key);
        int col = key_col(key);
        bool rfree = valid && !((rowdone[row >> 5] >> (row & 31)) & 1u);
        bool cfree = valid && !((coldone[col >> 5] >> (col & 31)) & 1u);
        u64 alive = __ballot(rfree && cfree);
        u64 comm = 0ull;
        while (alive) {
            int j = __ffsll((long long)alive) - 1;
            int rj = __shfl(row, j, 64);
            int cj = __shfl(col, j, 64);
            u64 conf = __ballot(row == rj || col == cj);  // includes j itself
            comm |= 1ull << j;
            alive &= ~conf;
        }
        if ((comm >> lane) & 1ull) {
            atomicOr(&rowdone[row >> 5], 1u << (row & 31));
            atomicOr(&coldone[col >> 5], 1u << (col & 31));
            actions[row] = (float)col;
        }
        assigned += __popcll(comm);
        key = nkey;
        __syncthreads();   // order this batch's LDS commits before next snapshot
    }

    // Exact-greedy fallback for rows that exhausted their top-16 (P ~ 2e-10).
    for (int guard = 0; assigned < K && guard < 2048; ++guard) {
        u64 best = 0ull;
        for (int r = 0; r < MROWS; ++r) {
            if ((rowdone[r >> 5] >> (r & 31)) & 1u) continue;
            const float* prow = policy + (size_t)r * NCOLS;
            u64 rowpart = (u64)(MROWS - 1 - r) << 12;
            for (int c = lane; c < NCOLS; c += 64) {
                if ((coldone[c >> 5] >> (c & 31)) & 1u) continue;
                u64 kk = ((u64)__float_as_uint(prow[c]) << 22) | rowpart |
                         (u64)(NCOLS - 1 - c);
                best = kk > best ? kk : best;
            }
        }
        best = wave_max_u64(best);
        if (best == 0ull) break;
        if (lane == 0) {
            int row = key_row(best), col = key_col(best);
            rowdone[row >> 5] |= 1u << (row & 31);
            coldone[col >> 5] |= 1u << (col & 31);
            actions[row] = (float)col;
        }
        ++assigned;
    }
}

extern "C" void kernel_launch(void* const* d_in, const int* in_sizes, int n_in,
                              void* d_out, int out_size, void* d_ws, size_t ws_size,
                              hipStream_t stream) {
    (void)in_sizes; (void)n_in; (void)out_size; (void)ws_size;
    const float* scores = (const float*)d_in[0];
    const int* cont = (const int*)d_in[1];
    const int* prev = (const int*)d_in[2];
    float* out = (float*)d_out;
    float* actions = out;
    float* policy = out + MROWS;

    char* ws = (char*)d_ws;
    float* pmax = (float*)(ws + 0);            // 256 f
    float* psum = (float*)(ws + 1024);         // 256 f
    unsigned* bitmap = (unsigned*)(ws + 2304); // 128 u32
    u64* keys16 = (u64*)(ws + 4096);           // 16384 u64 (sorted in place)

    k_partial_max<<<256, 256, 0, stream>>>(scores, pmax);
    k_partial_sum2<<<256, 256, 0, stream>>>(scores, pmax, psum, bitmap, cont, prev);
    k_policy_top16<<<MROWS, 256, 0, stream>>>(scores, pmax, psum, bitmap, cont,
                                              policy, keys16);
    s1_localsort<<<4, 1024, 0, stream>>>(keys16);
    s2_gpass<<<8, 1024, 0, stream>>>(keys16);
    s3_localfinish<<<4, 1024, 0, stream>>>(keys16);
    s45_gpass<<<4, 1024, 0, stream>>>(keys16);
    s6_localfinish<<<4, 1024, 0, stream>>>(keys16);
    k_scan<<<1, 64, 0, stream>>>(cont, prev, actions, keys16, bitmap, policy);
}